// Round 14
// baseline (141.091 us; speedup 1.0000x reference)
//
#include <hip/hip_runtime.h>
#include <math.h>

#define BB 16
#define LL 1024
#define DD 128
#define BL (BB*LL)
#define NDEPTH 4
#define EPSF 1e-5f

typedef unsigned short u16;
typedef short bf16x8 __attribute__((ext_vector_type(8)));
typedef short bf16x4 __attribute__((ext_vector_type(4)));
typedef float f32x4 __attribute__((ext_vector_type(4)));

static __device__ __forceinline__ u16 f2bf(float x) {
    unsigned u = __float_as_uint(x);
    u = u + 0x7fffu + ((u >> 16) & 1u);
    return (u16)(u >> 16);
}
static __device__ __forceinline__ float bf2f(short v) {
    return __uint_as_float(((unsigned)(unsigned short)v) << 16);
}
// gelu with A&S 7.1.26 erf approx (|eps|<1.5e-7), fast rcp/exp
static __device__ __forceinline__ float gelu_f(float x) {
    float u = x * 0.70710678118654752f;
    float au = fabsf(u);
    float t = __builtin_amdgcn_rcpf(1.0f + 0.3275911f * au);
    float poly = ((((1.061405429f * t - 1.453152027f) * t + 1.421413741f) * t
                   - 0.284496736f) * t + 0.254829592f) * t;
    float e = __expf(-u * u);
    float erfv = 1.0f - poly * e;
    erfv = copysignf(erfv, u);
    return 0.5f * x * (1.0f + erfv);
}

// LDS layout (mega, 32-token tile) — identical to the 135us R8/R13 kernel
#define DZ_B  0
#define S_B   15360
#define H1_B  23552
#define RST_B 39936
#define MRS_B 40064
#define LDS_TOT 40192

// ---------------------------------------------------------------- weight convert (identical to R8)
// theta(k>=1) -> frag-linear bf16 [slab][f:8][c:4][lane:64][8], PRE-SCALED by ln_g[d]/sqrt(2)
// w1 -> [layer][f:16][c:4][lane][8]; w2 -> [layer][f:8][c:8][lane][8]
#define N_TH (4*15*16384)
#define N_W1 (4*32768)
#define N_W2 (4*32768)
__global__ __launch_bounds__(256) void cvt_kernel(const float* __restrict__ theta,
        const float* __restrict__ fc1w, const float* __restrict__ fc2w,
        const float* __restrict__ ln_g,
        u16* __restrict__ thf, u16* __restrict__ w1f, u16* __restrict__ w2f) {
    int o = blockIdx.x * 256 + threadIdx.x;
    if (o < N_TH) {
        int j = o & 7, ln = (o >> 3) & 63, c = (o >> 9) & 3, f = (o >> 11) & 7;
        int slab = o >> 14;
        int layer = slab / 15, kk = slab - layer * 15;
        int h = f * 16 + (ln & 15), d = 32 * c + 8 * (ln >> 4) + j;
        float v = theta[(((size_t)layer * 16 + kk + 1) * 128 + h) * 128 + d];
        v *= ln_g[layer * 128 + d] * 0.70710678118654752f;
        thf[o] = f2bf(v);
    } else if (o < N_TH + N_W1) {
        int o2 = o - N_TH;
        int j = o2 & 7, ln = (o2 >> 3) & 63, c = (o2 >> 9) & 3, f = (o2 >> 11) & 15;
        int layer = o2 >> 15;
        int m = f * 16 + (ln & 15), d = 32 * c + 8 * (ln >> 4) + j;
        w1f[o2] = f2bf(fc1w[(size_t)layer * 32768 + m * 128 + d]);
    } else if (o < N_TH + N_W1 + N_W2) {
        int o2 = o - (N_TH + N_W1);
        int j = o2 & 7, ln = (o2 >> 3) & 63, c = (o2 >> 9) & 7, f = (o2 >> 12) & 7;
        int layer = o2 >> 15;
        int d = f * 16 + (ln & 15), m = 32 * c + 8 * (ln >> 4) + j;
        w2f[o2] = f2bf(fc2w[(size_t)layer * 32768 + d * 256 + m]);
    }
}

// ---------------------------------------------------------------- prep0: lift + LN-stats + z(bf16) + partials
__global__ __launch_bounds__(512) void prep0_kernel(const float* __restrict__ x,
        const float* __restrict__ lw, const float* __restrict__ lb,
        float* __restrict__ H, u16* __restrict__ Z,
        float* __restrict__ P1p, float* __restrict__ P2p) {
    __shared__ char lds[16384 + 256];
    float* rst = (float*)(lds + 16384);
    float* mrs = (float*)(lds + 16384 + 128);
    int b = blockIdx.y, nblk = blockIdx.x, t0 = nblk * 32, tid = threadIdx.x;

    #pragma unroll
    for (int it = 0; it < 2; ++it) {
        int idx = it * 512 + tid;
        int r = idx >> 5, d0 = (idx & 31) * 4;
        int l = t0 + r;
        float x0 = x[(size_t)b * 3072 + l];
        float x1 = x[(size_t)b * 3072 + 1024 + l];
        float x2 = x[(size_t)b * 3072 + 2048 + l];
        float coord = (float)l * (1.0f / 1023.0f);
        f32x4 hv;
        #pragma unroll
        for (int q = 0; q < 4; ++q) {
            int d = d0 + q;
            float4 w = *(const float4*)(lw + d * 4);
            hv[q] = lb[d] + w.x * x0 + w.y * x1 + w.z * x2 + w.w * coord;
        }
        *(f32x4*)(H + ((size_t)b * 1024 + l) * 128 + d0) = hv;
        int byte = r * 512 + ((d0 * 4) ^ ((r & 7) << 4));
        *(f32x4*)(lds + byte) = hv;
    }
    __syncthreads();
    {
        int t = tid >> 4, q = tid & 15;
        float s = 0.f, sq = 0.f;
        #pragma unroll
        for (int dd = 0; dd < 8; dd += 4) {
            int d = q * 8 + dd;
            int byte = t * 512 + ((d * 4) ^ ((t & 7) << 4));
            f32x4 v = *(const f32x4*)(lds + byte);
            s += v[0] + v[1] + v[2] + v[3];
            sq += v[0]*v[0] + v[1]*v[1] + v[2]*v[2] + v[3]*v[3];
        }
        #pragma unroll
        for (int o = 1; o < 16; o <<= 1) {
            s += __shfl_xor(s, o, 64); sq += __shfl_xor(sq, o, 64);
        }
        if (q == 0) {
            float mu = s * (1.f / 128.f);
            float var = sq * (1.f / 128.f) - mu * mu;
            float rs = rsqrtf(var + EPSF);
            rst[t] = rs; mrs[t] = mu * rs;
        }
    }
    __syncthreads();
    // ---- write z (bf16): one (r, d0-chunk) per thread
    {
        int r = tid >> 4, d0 = (tid & 15) * 8;
        int sw = (r & 7) << 4;
        f32x4 q1 = *(const f32x4*)(lds + r * 512 + ((d0 * 4) ^ sw));
        f32x4 q2 = *(const f32x4*)(lds + r * 512 + (((d0 + 4) * 4) ^ sw));
        float rs = rst[r], ms = mrs[r];
        u16 zo[8];
        #pragma unroll
        for (int j = 0; j < 4; ++j) zo[j] = f2bf(q1[j] * rs - ms);
        #pragma unroll
        for (int j = 0; j < 4; ++j) zo[4 + j] = f2bf(q2[j] * rs - ms);
        *(bf16x8*)(Z + ((size_t)b * 1024 + t0 + r) * 128 + d0) = *(bf16x8*)zo;
    }
    if (tid < 128) {
        float s = 0.f;
        #pragma unroll 8
        for (int t = 0; t < 32; ++t) {
            int byte = t * 512 + ((tid * 4) ^ ((t & 7) << 4));
            s += *(const float*)(lds + byte) * rst[t];
        }
        P1p[((size_t)b * 32 + nblk) * 128 + tid] = s;
    } else if (tid == 128) {
        float s = 0.f;
        for (int t = 0; t < 32; ++t) s += mrs[t];
        P2p[b * 32 + nblk] = s;
    }
}

// ---------------------------------------------------------------- C[b,h] (k=0 Haar row), grid (16 b, 8 hc)
__global__ __launch_bounds__(128) void c_kernel(const float* __restrict__ theta0,
        const float* __restrict__ P1p, const float* __restrict__ P2p,
        const float* __restrict__ lng, const float* __restrict__ lnb,
        float* __restrict__ C) {
    __shared__ float zsum[128];
    int b = blockIdx.x, hc = blockIdx.y, tid = threadIdx.x;
    float s = 0.f;
    #pragma unroll 8
    for (int j = 0; j < 32; ++j) s += P1p[((size_t)b * 32 + j) * 128 + tid];
    float p2 = 0.f;
    #pragma unroll 8
    for (int j = 0; j < 32; ++j) p2 += P2p[b * 32 + j];
    zsum[tid] = lng[tid] * (s - p2) + 1024.0f * lnb[tid];
    __syncthreads();
    int h = hc * 16 + (tid >> 3), q = tid & 7;
    const float* th = theta0 + h * 128 + q * 16;
    float acc = 0.f;
    #pragma unroll
    for (int d = 0; d < 16; d += 4) {
        float4 tv = *(const float4*)(th + d);
        acc += tv.x * zsum[q*16 + d] + tv.y * zsum[q*16 + d + 1]
             + tv.z * zsum[q*16 + d + 2] + tv.w * zsum[q*16 + d + 3];
    }
    acc += __shfl_xor(acc, 1, 64);
    acc += __shfl_xor(acc, 2, 64);
    acc += __shfl_xor(acc, 4, 64);
    if (q == 0) C[b * 128 + h] = acc * (1.0f / 32.0f);
}

// ---------------------------------------------------------------- mega (R13 structure; Phase B 4-chain ILP; stats folded into H)
// 512 threads (8 waves), 32-token tile, grid (32, 16) = 512 blocks = 2/CU.
template<int LAST>
__global__ __launch_bounds__(512, 4) void mega_kernel(
        const float* __restrict__ Hin, const u16* __restrict__ Zin,
        const u16* __restrict__ thf, const float* __restrict__ Cb_,
        const u16* __restrict__ w1f, const float* __restrict__ b1,
        const u16* __restrict__ w2f, const float* __restrict__ b2,
        float* __restrict__ Hout, u16* __restrict__ Zout,
        float* __restrict__ P1p, float* __restrict__ P2p,
        const float* __restrict__ hwp, const float* __restrict__ hbp,
        float* __restrict__ out) {
    __shared__ char lds[LDS_TOT];
    float* rst = (float*)(lds + RST_B);
    float* mrs = (float*)(lds + MRS_B);
    int b = blockIdx.y, nblk = blockIdx.x, n0 = nblk * 32, tid = threadIdx.x;

    // ---- Phase A: dz staging (60 halo rows) from pre-normalized z (bf16)
    const u16* Zb = Zin + (size_t)b * 1024 * 128;
    for (int c = tid; c < 60 * 16; c += 512) {
        int r = c >> 4, d0 = (c & 15) * 8;
        int gr = (n0 + r) & 1023, g1 = (n0 + r + 1) & 1023;
        bf16x8 za = *(const bf16x8*)(Zb + (size_t)gr * 128 + d0);
        bf16x8 zc = *(const bf16x8*)(Zb + (size_t)g1 * 128 + d0);
        u16 tmp[8];
        #pragma unroll
        for (int j = 0; j < 8; ++j)
            tmp[j] = f2bf(bf2f(za[j]) - bf2f(zc[j]));
        int byte = r * 256 + ((d0 * 2) ^ ((r & 7) << 4));
        *(bf16x8*)(lds + byte) = *(bf16x8*)tmp;
    }
    __syncthreads();

    int wave = tid >> 6, lane = tid & 63;
    int lm = lane & 15, lk = (lane >> 4) * 8;
    int fb = (wave & 3) * 2;            // S: wave h-frags {fb, fb+1}
    int tw0 = (wave >> 2) * 16;         // S: wave t-frag
    f32x4 zero4 = {0.f, 0.f, 0.f, 0.f};

    // ---- Phase B: S MFMA, 4 independent accumulator chains (even/odd it), unroll 8.
    f32x4 accS[2] = {zero4, zero4};
    f32x4 accT[2] = {zero4, zero4};
    {
        const u16* thl = thf + (size_t)lane * 8;
        #pragma unroll 8
        for (int it = 0; it < 60; ++it) {
            int kk = it >> 2, c4 = it & 3;
            bf16x8 afr0 = *(const bf16x8*)(thl + ((size_t)((kk * 8 + fb + 0) * 4 + c4) << 9));
            bf16x8 afr1 = *(const bf16x8*)(thl + ((size_t)((kk * 8 + fb + 1) * 4 + c4) << 9));
            int trow = tw0 + lm + 2 * kk;
            int byte = trow * 256 + (((c4 * 32 + lk) * 2) ^ ((trow & 7) << 4));
            bf16x8 bfr = *(const bf16x8*)(lds + byte);
            if (it & 1) {
                accT[0] = __builtin_amdgcn_mfma_f32_16x16x32_bf16(afr0, bfr, accT[0], 0, 0, 0);
                accT[1] = __builtin_amdgcn_mfma_f32_16x16x32_bf16(afr1, bfr, accT[1], 0, 0, 0);
            } else {
                accS[0] = __builtin_amdgcn_mfma_f32_16x16x32_bf16(afr0, bfr, accS[0], 0, 0, 0);
                accS[1] = __builtin_amdgcn_mfma_f32_16x16x32_bf16(afr1, bfr, accS[1], 0, 0, 0);
            }
        }
        accS[0] += accT[0];
        accS[1] += accT[1];
    }

    // ---- Phase C: S epilogue (+C), bf16 into S tile
    {
        const float* Crow = Cb_ + b * 128;
        int tl = tw0 + lm;
        #pragma unroll
        for (int mt = 0; mt < 2; ++mt) {
            int h0 = (fb + mt) * 16 + (lane >> 4) * 4;
            f32x4 cv = *(const f32x4*)(Crow + h0);
            u16 o[4];
            #pragma unroll
            for (int r = 0; r < 4; ++r) o[r] = f2bf(accS[mt][r] + cv[r]);
            int byte = S_B + tl * 256 + ((h0 * 2) ^ ((tl & 7) << 4));
            *(bf16x4*)(lds + byte) = *(bf16x4*)o;
        }
    }
    __syncthreads();

    // ---- Phase D: fc1 (A from global w1f) + GELU -> H1
    {
        f32x4 acc1[2][2];
        #pragma unroll
        for (int mt = 0; mt < 2; ++mt)
            #pragma unroll
            for (int nt = 0; nt < 2; ++nt) acc1[mt][nt] = zero4;
        const u16* w1l = w1f + (size_t)lane * 8;
        #pragma unroll
        for (int c4 = 0; c4 < 4; ++c4) {
            bf16x8 afr[2], bfr[2];
            #pragma unroll
            for (int mt = 0; mt < 2; ++mt)
                afr[mt] = *(const bf16x8*)(w1l + ((size_t)((wave * 2 + mt) * 4 + c4) << 9));
            #pragma unroll
            for (int nt = 0; nt < 2; ++nt) {
                int tl = nt * 16 + lm;
                int byte = S_B + tl * 256 + (((c4 * 32 + lk) * 2) ^ ((tl & 7) << 4));
                bfr[nt] = *(const bf16x8*)(lds + byte);
            }
            #pragma unroll
            for (int mt = 0; mt < 2; ++mt)
                #pragma unroll
                for (int nt = 0; nt < 2; ++nt)
                    acc1[mt][nt] = __builtin_amdgcn_mfma_f32_16x16x32_bf16(
                        afr[mt], bfr[nt], acc1[mt][nt], 0, 0, 0);
        }
        #pragma unroll
        for (int mt = 0; mt < 2; ++mt) {
            int mo = wave * 32 + mt * 16 + (lane >> 4) * 4;
            f32x4 bb4 = *(const f32x4*)(b1 + mo);
            #pragma unroll
            for (int nt = 0; nt < 2; ++nt) {
                int tl = nt * 16 + lm;
                u16 o[4];
                #pragma unroll
                for (int r = 0; r < 4; ++r)
                    o[r] = f2bf(gelu_f(acc1[mt][nt][r] + bb4[r]));
                int byte = H1_B + tl * 512 + ((mo * 2) ^ ((tl & 7) << 4));
                *(bf16x4*)(lds + byte) = *(bf16x4*)o;
            }
        }
    }
    __syncthreads();

    // ---- Phase F: fc2 (A from global w2f)
    f32x4 acc2[2] = {zero4, zero4};
    {
        const u16* w2l = w2f + (size_t)lane * 8;
        #pragma unroll
        for (int c8 = 0; c8 < 8; ++c8) {
            bf16x8 afr = *(const bf16x8*)(w2l + ((size_t)(wave * 8 + c8) << 9));
            #pragma unroll
            for (int nt = 0; nt < 2; ++nt) {
                int tl = nt * 16 + lm;
                int byte = H1_B + tl * 512 + (((c8 * 32 + lk) * 2) ^ ((tl & 7) << 4));
                bf16x8 bfr = *(const bf16x8*)(lds + byte);
                acc2[nt] = __builtin_amdgcn_mfma_f32_16x16x32_bf16(afr, bfr, acc2[nt], 0, 0, 0);
            }
        }
    }
    __syncthreads();

    // ---- Phase G: fc2 result f32 -> Ht [t][d] (reuse H1 region)
    {
        int dbase = wave * 16 + (lane >> 4) * 4;
        #pragma unroll
        for (int nt = 0; nt < 2; ++nt) {
            int tl = nt * 16 + lm;
            int byte = H1_B + tl * 512 + ((dbase * 4) ^ ((tl & 7) << 4));
            *(f32x4*)(lds + byte) = acc2[nt];
        }
    }
    __syncthreads();

    // ---- Phase H: residual writeback (+ head if LAST; + LN stats folded in if !LAST)
    {
        const float* Hrow = Hin + ((size_t)b * 1024 + n0) * 128;
        float* Horow = Hout + ((size_t)b * 1024 + n0) * 128;
        #pragma unroll
        for (int it = 0; it < 2; ++it) {
            int idx = it * 512 + tid;
            int r = idx >> 5, d0 = (idx & 31) * 4;
            int byte = H1_B + r * 512 + ((d0 * 4) ^ ((r & 7) << 4));
            f32x4 v = *(const f32x4*)(lds + byte);
            f32x4 bb = *(const f32x4*)(b2 + d0);
            f32x4 hv = *(const f32x4*)(Hrow + (size_t)r * 128 + d0);
            hv = hv + v + bb;
            if (LAST) {
                f32x4 wv = *(const f32x4*)(hwp + d0);
                float s = hv[0]*wv[0] + hv[1]*wv[1] + hv[2]*wv[2] + hv[3]*wv[3];
                #pragma unroll
                for (int o = 1; o < 32; o <<= 1) s += __shfl_xor(s, o, 64);
                if ((lane & 31) == 0) out[(size_t)b * 1024 + n0 + r] = s + hbp[0];
            } else {
                *(f32x4*)(Horow + (size_t)r * 128 + d0) = hv;
                *(f32x4*)(lds + byte) = hv;
                // LN stats from registers: 32 threads per row, width-32 reduce
                float s4  = hv[0] + hv[1] + hv[2] + hv[3];
                float sq4 = hv[0]*hv[0] + hv[1]*hv[1] + hv[2]*hv[2] + hv[3]*hv[3];
                #pragma unroll
                for (int o = 1; o < 32; o <<= 1) {
                    s4 += __shfl_xor(s4, o, 32); sq4 += __shfl_xor(sq4, o, 32);
                }
                if ((lane & 31) == 0) {
                    float mu = s4 * (1.f / 128.f);
                    float var = sq4 * (1.f / 128.f) - mu * mu;
                    float rs = rsqrtf(var + EPSF);
                    rst[r] = rs; mrs[r] = mu * rs;
                }
            }
        }
    }
    if (!LAST) {
        __syncthreads();
        // ---- Phase I2: write next-layer z (bf16): one (r, d0-chunk) per thread
        {
            int r = tid >> 4, d0 = (tid & 15) * 8;
            int sw = (r & 7) << 4;
            f32x4 q1 = *(const f32x4*)(lds + H1_B + r * 512 + ((d0 * 4) ^ sw));
            f32x4 q2 = *(const f32x4*)(lds + H1_B + r * 512 + (((d0 + 4) * 4) ^ sw));
            float rs = rst[r], ms = mrs[r];
            u16 zo[8];
            #pragma unroll
            for (int j = 0; j < 4; ++j) zo[j] = f2bf(q1[j] * rs - ms);
            #pragma unroll
            for (int j = 0; j < 4; ++j) zo[4 + j] = f2bf(q2[j] * rs - ms);
            *(bf16x8*)(Zout + ((size_t)b * 1024 + n0 + r) * 128 + d0) = *(bf16x8*)zo;
        }
        // ---- Phase J: partial column sums for next-layer C
        if (tid < 128) {
            float s = 0.f;
            #pragma unroll 8
            for (int t = 0; t < 32; ++t) {
                int byte = H1_B + t * 512 + ((tid * 4) ^ ((t & 7) << 4));
                s += *(const float*)(lds + byte) * rst[t];
            }
            P1p[((size_t)b * 32 + nblk) * 128 + tid] = s;
        } else if (tid == 128) {
            float s = 0.f;
            for (int t = 0; t < 32; ++t) s += mrs[t];
            P2p[b * 32 + nblk] = s;
        }
    }
}

// ----------------------------------------------------------------
extern "C" void kernel_launch(void* const* d_in, const int* in_sizes, int n_in,
                              void* d_out, int out_size, void* d_ws, size_t ws_size,
                              hipStream_t stream) {
    const float* x     = (const float*)d_in[0];
    const float* lw    = (const float*)d_in[1];
    const float* lb    = (const float*)d_in[2];
    // d_in[3] = Phi_f — analytically eliminated (Haar top-16 = const + finest 2-tap wavelets)
    const float* theta = (const float*)d_in[4];
    const float* ln_g  = (const float*)d_in[5];
    const float* ln_b  = (const float*)d_in[6];
    const float* fc1w  = (const float*)d_in[7];
    const float* fc1b  = (const float*)d_in[8];
    const float* fc2w  = (const float*)d_in[9];
    const float* fc2b  = (const float*)d_in[10];
    const float* hw    = (const float*)d_in[11];
    const float* hb    = (const float*)d_in[12];

    float* ws = (float*)d_ws;
    float* H_A = ws;                                   // 2M f32
    float* H_B = H_A + (size_t)BL * DD;                // 2M f32
    u16* Z_A = (u16*)(H_B + (size_t)BL * DD);          // 2M bf16
    u16* Z_B = Z_A + (size_t)BL * DD;                  // 2M bf16
    float* P1p = (float*)(Z_B + (size_t)BL * DD);      // 16*32*128
    float* P2p = P1p + 16 * 32 * 128;                  // 512
    float* Cb  = P2p + 512;                            // 2048
    u16* thf = (u16*)(Cb + 2048);                      // N_TH
    u16* w1f = thf + N_TH;                             // N_W1
    u16* w2f = w1f + N_W1;                             // N_W2

    cvt_kernel<<<(N_TH + N_W1 + N_W2) / 256, 256, 0, stream>>>(
        theta, fc1w, fc2w, ln_g, thf, w1f, w2f);
    prep0_kernel<<<dim3(32, 16), 512, 0, stream>>>(x, lw, lb, H_A, Z_A, P1p, P2p);

    float* Hi = H_A; float* Ho = H_B;
    u16* Zi = Z_A; u16* Zo = Z_B;
    for (int i = 0; i < NDEPTH; ++i) {
        c_kernel<<<dim3(16, 8), 128, 0, stream>>>(theta + (size_t)i * 16 * 16384, P1p, P2p,
                                                  ln_g + i * 128, ln_b + i * 128, Cb);
        if (i < NDEPTH - 1) {
            mega_kernel<0><<<dim3(32, 16), 512, 0, stream>>>(
                Hi, Zi,
                thf + (size_t)i * 15 * 16384, Cb,
                w1f + (size_t)i * 32768, fc1b + i * 256,
                w2f + (size_t)i * 32768, fc2b + i * 128,
                Ho, Zo, P1p, P2p, hw, hb, (float*)d_out);
        } else {
            mega_kernel<1><<<dim3(32, 16), 512, 0, stream>>>(
                Hi, Zi,
                thf + (size_t)i * 15 * 16384, Cb,
                w1f + (size_t)i * 32768, fc1b + i * 256,
                w2f + (size_t)i * 32768, fc2b + i * 128,
                Ho, Zo, P1p, P2p, hw, hb, (float*)d_out);
        }
        float* tH = Hi; Hi = Ho; Ho = tH;
        u16* tZ = Zi; Zi = Zo; Zo = tZ;
    }
}

// Round 15
// 135.191 us; speedup vs baseline: 1.0436x; 1.0436x over previous
//
#include <hip/hip_runtime.h>
#include <math.h>

#define BB 16
#define LL 1024
#define DD 128
#define BL (BB*LL)
#define NDEPTH 4
#define EPSF 1e-5f

typedef unsigned short u16;
typedef short bf16x8 __attribute__((ext_vector_type(8)));
typedef short bf16x4 __attribute__((ext_vector_type(4)));
typedef float f32x4 __attribute__((ext_vector_type(4)));

static __device__ __forceinline__ u16 f2bf(float x) {
    unsigned u = __float_as_uint(x);
    u = u + 0x7fffu + ((u >> 16) & 1u);
    return (u16)(u >> 16);
}
static __device__ __forceinline__ float bf2f(short v) {
    return __uint_as_float(((unsigned)(unsigned short)v) << 16);
}
// gelu with A&S 7.1.26 erf approx (|eps|<1.5e-7), fast rcp/exp
static __device__ __forceinline__ float gelu_f(float x) {
    float u = x * 0.70710678118654752f;
    float au = fabsf(u);
    float t = __builtin_amdgcn_rcpf(1.0f + 0.3275911f * au);
    float poly = ((((1.061405429f * t - 1.453152027f) * t + 1.421413741f) * t
                   - 0.284496736f) * t + 0.254829592f) * t;
    float e = __expf(-u * u);
    float erfv = 1.0f - poly * e;
    erfv = copysignf(erfv, u);
    return 0.5f * x * (1.0f + erfv);
}

// LDS layout (mega, 32-token tile) — identical to the 135us R8 kernel
#define DZ_B  0
#define S_B   15360
#define H1_B  23552
#define RST_B 39936
#define MRS_B 40064
#define LDS_TOT 40192

// ---------------------------------------------------------------- weight convert (identical to R8)
// theta(k>=1) -> frag-linear bf16 [slab][f:8][c:4][lane:64][8], PRE-SCALED by ln_g[d]/sqrt(2)
// w1 -> [layer][f:16][c:4][lane][8]; w2 -> [layer][f:8][c:8][lane][8]
#define N_TH (4*15*16384)
#define N_W1 (4*32768)
#define N_W2 (4*32768)
__global__ __launch_bounds__(256) void cvt_kernel(const float* __restrict__ theta,
        const float* __restrict__ fc1w, const float* __restrict__ fc2w,
        const float* __restrict__ ln_g,
        u16* __restrict__ thf, u16* __restrict__ w1f, u16* __restrict__ w2f) {
    int o = blockIdx.x * 256 + threadIdx.x;
    if (o < N_TH) {
        int j = o & 7, ln = (o >> 3) & 63, c = (o >> 9) & 3, f = (o >> 11) & 7;
        int slab = o >> 14;
        int layer = slab / 15, kk = slab - layer * 15;
        int h = f * 16 + (ln & 15), d = 32 * c + 8 * (ln >> 4) + j;
        float v = theta[(((size_t)layer * 16 + kk + 1) * 128 + h) * 128 + d];
        v *= ln_g[layer * 128 + d] * 0.70710678118654752f;
        thf[o] = f2bf(v);
    } else if (o < N_TH + N_W1) {
        int o2 = o - N_TH;
        int j = o2 & 7, ln = (o2 >> 3) & 63, c = (o2 >> 9) & 3, f = (o2 >> 11) & 15;
        int layer = o2 >> 15;
        int m = f * 16 + (ln & 15), d = 32 * c + 8 * (ln >> 4) + j;
        w1f[o2] = f2bf(fc1w[(size_t)layer * 32768 + m * 128 + d]);
    } else if (o < N_TH + N_W1 + N_W2) {
        int o2 = o - (N_TH + N_W1);
        int j = o2 & 7, ln = (o2 >> 3) & 63, c = (o2 >> 9) & 7, f = (o2 >> 12) & 7;
        int layer = o2 >> 15;
        int d = f * 16 + (ln & 15), m = 32 * c + 8 * (ln >> 4) + j;
        w2f[o2] = f2bf(fc2w[(size_t)layer * 32768 + d * 256 + m]);
    }
}

// ---------------------------------------------------------------- prep0: lift + LN-stats + z(bf16) + partials
__global__ __launch_bounds__(512) void prep0_kernel(const float* __restrict__ x,
        const float* __restrict__ lw, const float* __restrict__ lb,
        float* __restrict__ H, u16* __restrict__ Z,
        float* __restrict__ P1p, float* __restrict__ P2p) {
    __shared__ char lds[16384 + 256];
    float* rst = (float*)(lds + 16384);
    float* mrs = (float*)(lds + 16384 + 128);
    int b = blockIdx.y, nblk = blockIdx.x, t0 = nblk * 32, tid = threadIdx.x;

    #pragma unroll
    for (int it = 0; it < 2; ++it) {
        int idx = it * 512 + tid;
        int r = idx >> 5, d0 = (idx & 31) * 4;
        int l = t0 + r;
        float x0 = x[(size_t)b * 3072 + l];
        float x1 = x[(size_t)b * 3072 + 1024 + l];
        float x2 = x[(size_t)b * 3072 + 2048 + l];
        float coord = (float)l * (1.0f / 1023.0f);
        f32x4 hv;
        #pragma unroll
        for (int q = 0; q < 4; ++q) {
            int d = d0 + q;
            float4 w = *(const float4*)(lw + d * 4);
            hv[q] = lb[d] + w.x * x0 + w.y * x1 + w.z * x2 + w.w * coord;
        }
        *(f32x4*)(H + ((size_t)b * 1024 + l) * 128 + d0) = hv;
        int byte = r * 512 + ((d0 * 4) ^ ((r & 7) << 4));
        *(f32x4*)(lds + byte) = hv;
    }
    __syncthreads();
    {
        int t = tid >> 4, q = tid & 15;
        float s = 0.f, sq = 0.f;
        #pragma unroll
        for (int dd = 0; dd < 8; dd += 4) {
            int d = q * 8 + dd;
            int byte = t * 512 + ((d * 4) ^ ((t & 7) << 4));
            f32x4 v = *(const f32x4*)(lds + byte);
            s += v[0] + v[1] + v[2] + v[3];
            sq += v[0]*v[0] + v[1]*v[1] + v[2]*v[2] + v[3]*v[3];
        }
        #pragma unroll
        for (int o = 1; o < 16; o <<= 1) {
            s += __shfl_xor(s, o, 64); sq += __shfl_xor(sq, o, 64);
        }
        if (q == 0) {
            float mu = s * (1.f / 128.f);
            float var = sq * (1.f / 128.f) - mu * mu;
            float rs = rsqrtf(var + EPSF);
            rst[t] = rs; mrs[t] = mu * rs;
        }
    }
    __syncthreads();
    // ---- write z (bf16): one (r, d0-chunk) per thread
    {
        int r = tid >> 4, d0 = (tid & 15) * 8;
        int sw = (r & 7) << 4;
        f32x4 q1 = *(const f32x4*)(lds + r * 512 + ((d0 * 4) ^ sw));
        f32x4 q2 = *(const f32x4*)(lds + r * 512 + (((d0 + 4) * 4) ^ sw));
        float rs = rst[r], ms = mrs[r];
        u16 zo[8];
        #pragma unroll
        for (int j = 0; j < 4; ++j) zo[j] = f2bf(q1[j] * rs - ms);
        #pragma unroll
        for (int j = 0; j < 4; ++j) zo[4 + j] = f2bf(q2[j] * rs - ms);
        *(bf16x8*)(Z + ((size_t)b * 1024 + t0 + r) * 128 + d0) = *(bf16x8*)zo;
    }
    if (tid < 128) {
        float s = 0.f;
        #pragma unroll 8
        for (int t = 0; t < 32; ++t) {
            int byte = t * 512 + ((tid * 4) ^ ((t & 7) << 4));
            s += *(const float*)(lds + byte) * rst[t];
        }
        P1p[((size_t)b * 32 + nblk) * 128 + tid] = s;
    } else if (tid == 128) {
        float s = 0.f;
        for (int t = 0; t < 32; ++t) s += mrs[t];
        P2p[b * 32 + nblk] = s;
    }
}

// ---------------------------------------------------------------- C[b,h] (k=0 Haar row), grid (16 b, 8 hc)
__global__ __launch_bounds__(128) void c_kernel(const float* __restrict__ theta0,
        const float* __restrict__ P1p, const float* __restrict__ P2p,
        const float* __restrict__ lng, const float* __restrict__ lnb,
        float* __restrict__ C) {
    __shared__ float zsum[128];
    int b = blockIdx.x, hc = blockIdx.y, tid = threadIdx.x;
    float s = 0.f;
    #pragma unroll 8
    for (int j = 0; j < 32; ++j) s += P1p[((size_t)b * 32 + j) * 128 + tid];
    float p2 = 0.f;
    #pragma unroll 8
    for (int j = 0; j < 32; ++j) p2 += P2p[b * 32 + j];
    zsum[tid] = lng[tid] * (s - p2) + 1024.0f * lnb[tid];
    __syncthreads();
    int h = hc * 16 + (tid >> 3), q = tid & 7;
    const float* th = theta0 + h * 128 + q * 16;
    float acc = 0.f;
    #pragma unroll
    for (int d = 0; d < 16; d += 4) {
        float4 tv = *(const float4*)(th + d);
        acc += tv.x * zsum[q*16 + d] + tv.y * zsum[q*16 + d + 1]
             + tv.z * zsum[q*16 + d + 2] + tv.w * zsum[q*16 + d + 3];
    }
    acc += __shfl_xor(acc, 1, 64);
    acc += __shfl_xor(acc, 2, 64);
    acc += __shfl_xor(acc, 4, 64);
    if (q == 0) C[b * 128 + h] = acc * (1.0f / 32.0f);
}

// ---------------------------------------------------------------- mega (R8 structure; Phase A reads z bf16)
// 512 threads (8 waves), 32-token tile, grid (32, 16) = 512 blocks = 2/CU.
template<int LAST>
__global__ __launch_bounds__(512, 4) void mega_kernel(
        const float* __restrict__ Hin, const u16* __restrict__ Zin,
        const u16* __restrict__ thf, const float* __restrict__ Cb_,
        const u16* __restrict__ w1f, const float* __restrict__ b1,
        const u16* __restrict__ w2f, const float* __restrict__ b2,
        float* __restrict__ Hout, u16* __restrict__ Zout,
        float* __restrict__ P1p, float* __restrict__ P2p,
        const float* __restrict__ hwp, const float* __restrict__ hbp,
        float* __restrict__ out) {
    __shared__ char lds[LDS_TOT];
    int b = blockIdx.y, nblk = blockIdx.x, n0 = nblk * 32, tid = threadIdx.x;

    // ---- Phase A: dz staging (60 halo rows) from pre-normalized z (bf16)
    const u16* Zb = Zin + (size_t)b * 1024 * 128;
    for (int c = tid; c < 60 * 16; c += 512) {
        int r = c >> 4, d0 = (c & 15) * 8;
        int gr = (n0 + r) & 1023, g1 = (n0 + r + 1) & 1023;
        bf16x8 za = *(const bf16x8*)(Zb + (size_t)gr * 128 + d0);
        bf16x8 zc = *(const bf16x8*)(Zb + (size_t)g1 * 128 + d0);
        u16 tmp[8];
        #pragma unroll
        for (int j = 0; j < 8; ++j)
            tmp[j] = f2bf(bf2f(za[j]) - bf2f(zc[j]));
        int byte = r * 256 + ((d0 * 2) ^ ((r & 7) << 4));
        *(bf16x8*)(lds + byte) = *(bf16x8*)tmp;
    }
    __syncthreads();

    int wave = tid >> 6, lane = tid & 63;
    int lm = lane & 15, lk = (lane >> 4) * 8;
    int fb = (wave & 3) * 2;            // S: wave h-frags {fb, fb+1}
    int tw0 = (wave >> 2) * 16;         // S: wave t-frag
    f32x4 zero4 = {0.f, 0.f, 0.f, 0.f};

    // ---- Phase B: S MFMA. A-frags stream from global (frag-linear). No barriers.
    f32x4 accS[2] = {zero4, zero4};
    {
        const u16* thl = thf + (size_t)lane * 8;
        #pragma unroll 4
        for (int it = 0; it < 60; ++it) {
            int kk = it >> 2, c4 = it & 3;
            bf16x8 afr0 = *(const bf16x8*)(thl + ((size_t)((kk * 8 + fb + 0) * 4 + c4) << 9));
            bf16x8 afr1 = *(const bf16x8*)(thl + ((size_t)((kk * 8 + fb + 1) * 4 + c4) << 9));
            int trow = tw0 + lm + 2 * kk;
            int byte = trow * 256 + (((c4 * 32 + lk) * 2) ^ ((trow & 7) << 4));
            bf16x8 bfr = *(const bf16x8*)(lds + byte);
            accS[0] = __builtin_amdgcn_mfma_f32_16x16x32_bf16(afr0, bfr, accS[0], 0, 0, 0);
            accS[1] = __builtin_amdgcn_mfma_f32_16x16x32_bf16(afr1, bfr, accS[1], 0, 0, 0);
        }
    }

    // ---- Phase C: S epilogue (+C), bf16 into S tile
    {
        const float* Crow = Cb_ + b * 128;
        int tl = tw0 + lm;
        #pragma unroll
        for (int mt = 0; mt < 2; ++mt) {
            int h0 = (fb + mt) * 16 + (lane >> 4) * 4;
            f32x4 cv = *(const f32x4*)(Crow + h0);
            u16 o[4];
            #pragma unroll
            for (int r = 0; r < 4; ++r) o[r] = f2bf(accS[mt][r] + cv[r]);
            int byte = S_B + tl * 256 + ((h0 * 2) ^ ((tl & 7) << 4));
            *(bf16x4*)(lds + byte) = *(bf16x4*)o;
        }
    }
    __syncthreads();

    // ---- Phase D: fc1 (A from global w1f) + GELU -> H1
    {
        f32x4 acc1[2][2];
        #pragma unroll
        for (int mt = 0; mt < 2; ++mt)
            #pragma unroll
            for (int nt = 0; nt < 2; ++nt) acc1[mt][nt] = zero4;
        const u16* w1l = w1f + (size_t)lane * 8;
        #pragma unroll
        for (int c4 = 0; c4 < 4; ++c4) {
            bf16x8 afr[2], bfr[2];
            #pragma unroll
            for (int mt = 0; mt < 2; ++mt)
                afr[mt] = *(const bf16x8*)(w1l + ((size_t)((wave * 2 + mt) * 4 + c4) << 9));
            #pragma unroll
            for (int nt = 0; nt < 2; ++nt) {
                int tl = nt * 16 + lm;
                int byte = S_B + tl * 256 + (((c4 * 32 + lk) * 2) ^ ((tl & 7) << 4));
                bfr[nt] = *(const bf16x8*)(lds + byte);
            }
            #pragma unroll
            for (int mt = 0; mt < 2; ++mt)
                #pragma unroll
                for (int nt = 0; nt < 2; ++nt)
                    acc1[mt][nt] = __builtin_amdgcn_mfma_f32_16x16x32_bf16(
                        afr[mt], bfr[nt], acc1[mt][nt], 0, 0, 0);
        }
        #pragma unroll
        for (int mt = 0; mt < 2; ++mt) {
            int mo = wave * 32 + mt * 16 + (lane >> 4) * 4;
            f32x4 bb4 = *(const f32x4*)(b1 + mo);
            #pragma unroll
            for (int nt = 0; nt < 2; ++nt) {
                int tl = nt * 16 + lm;
                u16 o[4];
                #pragma unroll
                for (int r = 0; r < 4; ++r)
                    o[r] = f2bf(gelu_f(acc1[mt][nt][r] + bb4[r]));
                int byte = H1_B + tl * 512 + ((mo * 2) ^ ((tl & 7) << 4));
                *(bf16x4*)(lds + byte) = *(bf16x4*)o;
            }
        }
    }
    __syncthreads();

    // ---- Phase F: fc2 (A from global w2f)
    f32x4 acc2[2] = {zero4, zero4};
    {
        const u16* w2l = w2f + (size_t)lane * 8;
        #pragma unroll
        for (int c8 = 0; c8 < 8; ++c8) {
            bf16x8 afr = *(const bf16x8*)(w2l + ((size_t)(wave * 8 + c8) << 9));
            #pragma unroll
            for (int nt = 0; nt < 2; ++nt) {
                int tl = nt * 16 + lm;
                int byte = H1_B + tl * 512 + (((c8 * 32 + lk) * 2) ^ ((tl & 7) << 4));
                bf16x8 bfr = *(const bf16x8*)(lds + byte);
                acc2[nt] = __builtin_amdgcn_mfma_f32_16x16x32_bf16(afr, bfr, acc2[nt], 0, 0, 0);
            }
        }
    }
    __syncthreads();

    // ---- Phase G: fc2 result f32 -> Ht [t][d] (reuse H1 region)
    {
        int dbase = wave * 16 + (lane >> 4) * 4;
        #pragma unroll
        for (int nt = 0; nt < 2; ++nt) {
            int tl = nt * 16 + lm;
            int byte = H1_B + tl * 512 + ((dbase * 4) ^ ((tl & 7) << 4));
            *(f32x4*)(lds + byte) = acc2[nt];
        }
    }
    __syncthreads();

    // ---- Phase H: residual writeback (+ head if LAST)
    {
        const float* Hrow = Hin + ((size_t)b * 1024 + n0) * 128;
        float* Horow = Hout + ((size_t)b * 1024 + n0) * 128;
        #pragma unroll
        for (int it = 0; it < 2; ++it) {
            int idx = it * 512 + tid;
            int r = idx >> 5, d0 = (idx & 31) * 4;
            int byte = H1_B + r * 512 + ((d0 * 4) ^ ((r & 7) << 4));
            f32x4 v = *(const f32x4*)(lds + byte);
            f32x4 bb = *(const f32x4*)(b2 + d0);
            f32x4 hv = *(const f32x4*)(Hrow + (size_t)r * 128 + d0);
            hv = hv + v + bb;
            if (LAST) {
                f32x4 wv = *(const f32x4*)(hwp + d0);
                float s = hv[0]*wv[0] + hv[1]*wv[1] + hv[2]*wv[2] + hv[3]*wv[3];
                #pragma unroll
                for (int o = 1; o < 32; o <<= 1) s += __shfl_xor(s, o, 64);
                if ((lane & 31) == 0) out[(size_t)b * 1024 + n0 + r] = s + hbp[0];
            } else {
                *(f32x4*)(Horow + (size_t)r * 128 + d0) = hv;
                *(f32x4*)(lds + byte) = hv;
            }
        }
    }
    if (!LAST) {
        __syncthreads();
        // ---- Phase I: next-layer LN stats
        float* rst = (float*)(lds + RST_B);
        float* mrs = (float*)(lds + MRS_B);
        {
            int t = tid >> 4, q = tid & 15;
            float s = 0.f, sq = 0.f;
            #pragma unroll
            for (int dd = 0; dd < 8; dd += 4) {
                int d = q * 8 + dd;
                int byte = H1_B + t * 512 + ((d * 4) ^ ((t & 7) << 4));
                f32x4 v = *(const f32x4*)(lds + byte);
                s += v[0] + v[1] + v[2] + v[3];
                sq += v[0]*v[0] + v[1]*v[1] + v[2]*v[2] + v[3]*v[3];
            }
            #pragma unroll
            for (int o = 1; o < 16; o <<= 1) {
                s += __shfl_xor(s, o, 64); sq += __shfl_xor(sq, o, 64);
            }
            if (q == 0) {
                float mu = s * (1.f / 128.f);
                float var = sq * (1.f / 128.f) - mu * mu;
                float rs = rsqrtf(var + EPSF);
                rst[t] = rs; mrs[t] = mu * rs;
            }
        }
        __syncthreads();
        // ---- Phase I2: write next-layer z (bf16): one (r, d0-chunk) per thread
        {
            int r = tid >> 4, d0 = (tid & 15) * 8;
            int sw = (r & 7) << 4;
            f32x4 q1 = *(const f32x4*)(lds + H1_B + r * 512 + ((d0 * 4) ^ sw));
            f32x4 q2 = *(const f32x4*)(lds + H1_B + r * 512 + (((d0 + 4) * 4) ^ sw));
            float rs = rst[r], ms = mrs[r];
            u16 zo[8];
            #pragma unroll
            for (int j = 0; j < 4; ++j) zo[j] = f2bf(q1[j] * rs - ms);
            #pragma unroll
            for (int j = 0; j < 4; ++j) zo[4 + j] = f2bf(q2[j] * rs - ms);
            *(bf16x8*)(Zout + ((size_t)b * 1024 + n0 + r) * 128 + d0) = *(bf16x8*)zo;
        }
        // ---- Phase J: partial column sums for next-layer C
        if (tid < 128) {
            float s = 0.f;
            #pragma unroll 8
            for (int t = 0; t < 32; ++t) {
                int byte = H1_B + t * 512 + ((tid * 4) ^ ((t & 7) << 4));
                s += *(const float*)(lds + byte) * rst[t];
            }
            P1p[((size_t)b * 32 + nblk) * 128 + tid] = s;
        } else if (tid == 128) {
            float s = 0.f;
            for (int t = 0; t < 32; ++t) s += mrs[t];
            P2p[b * 32 + nblk] = s;
        }
    }
}

// ----------------------------------------------------------------
extern "C" void kernel_launch(void* const* d_in, const int* in_sizes, int n_in,
                              void* d_out, int out_size, void* d_ws, size_t ws_size,
                              hipStream_t stream) {
    const float* x     = (const float*)d_in[0];
    const float* lw    = (const float*)d_in[1];
    const float* lb    = (const float*)d_in[2];
    // d_in[3] = Phi_f — analytically eliminated (Haar top-16 = const + finest 2-tap wavelets)
    const float* theta = (const float*)d_in[4];
    const float* ln_g  = (const float*)d_in[5];
    const float* ln_b  = (const float*)d_in[6];
    const float* fc1w  = (const float*)d_in[7];
    const float* fc1b  = (const float*)d_in[8];
    const float* fc2w  = (const float*)d_in[9];
    const float* fc2b  = (const float*)d_in[10];
    const float* hw    = (const float*)d_in[11];
    const float* hb    = (const float*)d_in[12];

    float* ws = (float*)d_ws;
    float* H_A = ws;                                   // 2M f32
    float* H_B = H_A + (size_t)BL * DD;                // 2M f32
    u16* Z_A = (u16*)(H_B + (size_t)BL * DD);          // 2M bf16
    u16* Z_B = Z_A + (size_t)BL * DD;                  // 2M bf16
    float* P1p = (float*)(Z_B + (size_t)BL * DD);      // 16*32*128
    float* P2p = P1p + 16 * 32 * 128;                  // 512
    float* Cb  = P2p + 512;                            // 2048
    u16* thf = (u16*)(Cb + 2048);                      // N_TH
    u16* w1f = thf + N_TH;                             // N_W1
    u16* w2f = w1f + N_W1;                             // N_W2

    cvt_kernel<<<(N_TH + N_W1 + N_W2) / 256, 256, 0, stream>>>(
        theta, fc1w, fc2w, ln_g, thf, w1f, w2f);
    prep0_kernel<<<dim3(32, 16), 512, 0, stream>>>(x, lw, lb, H_A, Z_A, P1p, P2p);

    float* Hi = H_A; float* Ho = H_B;
    u16* Zi = Z_A; u16* Zo = Z_B;
    for (int i = 0; i < NDEPTH; ++i) {
        c_kernel<<<dim3(16, 8), 128, 0, stream>>>(theta + (size_t)i * 16 * 16384, P1p, P2p,
                                                  ln_g + i * 128, ln_b + i * 128, Cb);
        if (i < NDEPTH - 1) {
            mega_kernel<0><<<dim3(32, 16), 512, 0, stream>>>(
                Hi, Zi,
                thf + (size_t)i * 15 * 16384, Cb,
                w1f + (size_t)i * 32768, fc1b + i * 256,
                w2f + (size_t)i * 32768, fc2b + i * 128,
                Ho, Zo, P1p, P2p, hw, hb, (float*)d_out);
        } else {
            mega_kernel<1><<<dim3(32, 16), 512, 0, stream>>>(
                Hi, Zi,
                thf + (size_t)i * 15 * 16384, Cb,
                w1f + (size_t)i * 32768, fc1b + i * 256,
                w2f + (size_t)i * 32768, fc2b + i * 128,
                Ho, Zo, P1p, P2p, hw, hb, (float*)d_out);
        }
        float* tH = Hi; Hi = Ho; Ho = tH;
        u16* tZ = Zi; Zi = Zo; Zo = tZ;
    }
}